// Round 1
// 1044.656 us; speedup vs baseline: 1.0901x; 1.0901x over previous
//
#include <hip/hip_runtime.h>
#include <math.h>

#define CDIM 128
#define EDIM 512
#define BLK 256
#define MT 64                 // vectors per block
#define ECH 64                // embedding chunk
#define NVEC 262144           // 8*32*32*32
#define SPATIAL 32768
#define QELEMS 33554432LL
#define TIE_T 4e-6f

typedef __bf16 bf16x8 __attribute__((ext_vector_type(8)));
typedef float  f32x4  __attribute__((ext_vector_type(4)));

struct WS {
  float  wnh[EDIM];           // 0.5*||e||^2
  int    counts[EDIM];
  double lossAcc;
  double _pad;                // align wp to 16B
  unsigned int wp[EDIM * CDIM];   // packed bf16 split: (hi<<16)|lo
};

__device__ inline unsigned short f2bf(float f) {
  unsigned u = __float_as_uint(f);
  return (unsigned short)((u + 0x7fffu + ((u >> 16) & 1u)) >> 16);   // RNE
}
__device__ inline float bf2f(unsigned short h) {
  return __uint_as_float(((unsigned)h) << 16);
}

// ---- pre-pass: half norms, zero accumulators, bf16 hi/lo split of w
__global__ __launch_bounds__(512) void vq_pre(const float* __restrict__ wt,
                                              WS* __restrict__ ws, int buildWP) {
  int t = threadIdx.x;
  const float* w = wt + (size_t)t * CDIM;
  float a0 = 0.f, a1 = 0.f, a2 = 0.f, a3 = 0.f;
#pragma unroll
  for (int c = 0; c < CDIM; c += 4) {
    a0 = fmaf(w[c + 0], w[c + 0], a0);
    a1 = fmaf(w[c + 1], w[c + 1], a1);
    a2 = fmaf(w[c + 2], w[c + 2], a2);
    a3 = fmaf(w[c + 3], w[c + 3], a3);
  }
  ws->wnh[t] = 0.5f * ((a0 + a1) + (a2 + a3));
  ws->counts[t] = 0;
  if (t == 0) ws->lossAcc = 0.0;
  if (buildWP) {
    for (int c = 0; c < CDIM; ++c) {
      float f = w[c];
      unsigned short h = f2bf(f);
      unsigned short l = f2bf(f - bf2f(h));
      ws->wp[(size_t)t * CDIM + c] = (((unsigned)h) << 16) | (unsigned)l;
    }
  }
}

__device__ double score64(const float* __restrict__ in, const float* __restrict__ wt,
                          size_t xoff, int e) {
  const float* w = wt + (size_t)e * CDIM;
  double a = 0.0;
  for (int c = 0; c < CDIM; ++c) {
    double wd = (double)w[c];
    double xv = (double)in[xoff + (size_t)c * SPATIAL];
    a = fma(wd, fma(0.5, wd, -xv), a);    // 0.5||e||^2 - x.e, exact ordering
  }
  return a;
}

// x LDS layout (bf16, per hi/lo array):
//   elem(m,k) = (m>>4)*2176 + (k>>3)*136 + (m&15)*8 + (k&7)
//   -> one B-fragment (16 m x 8 consecutive k per lane) = one aligned ds_read_b128,
//      conflict-free (16-lane phase covers all 32 banks).
// w LDS layout: row-major [e][k], row stride 136 elems (272B, 16B-aligned, pad kills
//   the power-of-2 row stride).

template <bool USEWP>
__global__ __launch_bounds__(BLK, 2) void vq_main(const float* __restrict__ in,
                                                  const float* __restrict__ wt,
                                                  WS* __restrict__ ws,
                                                  float* __restrict__ out_q,
                                                  float* __restrict__ enc) {
  __shared__ __align__(16) unsigned short xhi[4 * 2176];   // 17408 B
  __shared__ __align__(16) unsigned short xlo[4 * 2176];   // 17408 B
  __shared__ __align__(16) char wuni[2 * ECH * 136 * 2];   // w hi/lo (34816 B); merge overlay
  __shared__ float  wn_l[EDIM];
  __shared__ int    hist[EDIM];
  __shared__ int    sIdx[MT];
  __shared__ double lred[BLK];

  unsigned short* whl = (unsigned short*)wuni;             // [ECH][136]
  unsigned short* wll = whl + ECH * 136;

  const int tid = threadIdx.x;
  for (int e = tid; e < EDIM; e += BLK) { wn_l[e] = ws->wnh[e]; hist[e] = 0; }

  const int n0 = blockIdx.x * MT;
  const int b  = n0 >> 15;
  const int s0 = n0 & (SPATIAL - 1);
  const size_t ibase = (size_t)b * CDIM * SPATIAL;

  // ---- stage x: fp32 -> bf16 hi/lo into subtiled LDS (done once, reused for loss)
  {
    const int mq = tid & 15;          // m-quad: m0 = 4*mq
    const int cr = tid >> 4;          // 0..15
    const int m0 = mq * 4;
#pragma unroll
    for (int p = 0; p < 8; ++p) {
      int c = cr + p * 16;
      float4 v = *(const float4*)(in + ibase + (size_t)c * SPATIAL + s0 + m0);
      int sb = (m0 >> 4) * 2176 + (c >> 3) * 136 + (m0 & 15) * 8 + (c & 7);
#pragma unroll
      for (int i = 0; i < 4; ++i) {
        float f = ((const float*)&v)[i];
        unsigned short h = f2bf(f);
        unsigned short l = f2bf(f - bf2f(h));
        xhi[sb + i * 8] = h;
        xlo[sb + i * 8] = l;
      }
    }
  }

  const int lane = tid & 63, wv = tid >> 6;
  const int col = lane & 15, g = lane >> 4;

  // per-lane running top-3 per owned m-column (4 mt slots)
  float b1[4], b2[4], b3[4]; int i1[4], i2[4];
#pragma unroll
  for (int i = 0; i < 4; ++i) { b1[i] = 1e30f; b2[i] = 1e30f; b3[i] = 1e30f; i1[i] = 0; i2[i] = 0; }

  for (int ch = 0; ch < 8; ++ch) {
    const int e0c = ch * ECH;
    __syncthreads();                  // also covers x staging / prior chunk readers
    // ---- stage w chunk -> LDS hi/lo
    if (USEWP) {
      const uint4* wp4 = (const uint4*)(ws->wp + (size_t)e0c * CDIM);
#pragma unroll
      for (int i = 0; i < 8; ++i) {
        int q = i * BLK + tid;        // 0..2047
        int e = q >> 5, k0 = (q & 31) * 4;
        uint4 W = wp4[q];
        unsigned hi01 = __builtin_amdgcn_perm(W.y, W.x, 0x07060302u);
        unsigned lo01 = __builtin_amdgcn_perm(W.y, W.x, 0x05040100u);
        unsigned hi23 = __builtin_amdgcn_perm(W.w, W.z, 0x07060302u);
        unsigned lo23 = __builtin_amdgcn_perm(W.w, W.z, 0x05040100u);
        *(uint2*)&whl[e * 136 + k0] = make_uint2(hi01, hi23);
        *(uint2*)&wll[e * 136 + k0] = make_uint2(lo01, lo23);
      }
    } else {
      const float* wbase = wt + (size_t)e0c * CDIM;
#pragma unroll
      for (int i = 0; i < 8; ++i) {
        int q = i * BLK + tid;
        int e = q >> 5, k0 = (q & 31) * 4;
        float4 F = *(const float4*)(wbase + (size_t)e * CDIM + k0);
        unsigned short h0 = f2bf(F.x), h1 = f2bf(F.y), h2 = f2bf(F.z), h3 = f2bf(F.w);
        unsigned short l0 = f2bf(F.x - bf2f(h0)), l1 = f2bf(F.y - bf2f(h1));
        unsigned short l2 = f2bf(F.z - bf2f(h2)), l3 = f2bf(F.w - bf2f(h3));
        *(uint2*)&whl[e * 136 + k0] =
            make_uint2((unsigned)h0 | ((unsigned)h1 << 16), (unsigned)h2 | ((unsigned)h3 << 16));
        *(uint2*)&wll[e * 136 + k0] =
            make_uint2((unsigned)l0 | ((unsigned)l1 << 16), (unsigned)l2 | ((unsigned)l3 << 16));
      }
    }
    __syncthreads();

    // ---- A fragments (w rows of this wave's 16-row e-tile)
    bf16x8 ah[4], al[4];
#pragma unroll
    for (int kt = 0; kt < 4; ++kt) {
      int rowb = (wv * 16 + col) * 136 + kt * 32 + g * 8;
      ah[kt] = *(const bf16x8*)&whl[rowb];
      al[kt] = *(const bf16x8*)&wll[rowb];
    }

    // ---- MFMA: D[e][m] = sum_k w*x via 4-pass bf16 split (near-fp32 exact)
    f32x4 acc[4];
#pragma unroll
    for (int mt = 0; mt < 4; ++mt) {
      f32x4 a = {0.f, 0.f, 0.f, 0.f};
#pragma unroll
      for (int kt = 0; kt < 4; ++kt) {
        int xb = mt * 2176 + (kt * 4 + g) * 136 + col * 8;
        bf16x8 bh = *(const bf16x8*)&xhi[xb];
        bf16x8 bl = *(const bf16x8*)&xlo[xb];
        a = __builtin_amdgcn_mfma_f32_16x16x32_bf16(ah[kt], bh, a, 0, 0, 0);
        a = __builtin_amdgcn_mfma_f32_16x16x32_bf16(ah[kt], bl, a, 0, 0, 0);
        a = __builtin_amdgcn_mfma_f32_16x16x32_bf16(al[kt], bh, a, 0, 0, 0);
        a = __builtin_amdgcn_mfma_f32_16x16x32_bf16(al[kt], bl, a, 0, 0, 0);
      }
      acc[mt] = a;
    }

    // ---- epilogue: scores + per-lane top-3 (e ascending -> first-index ties)
    const int e0 = e0c + wv * 16 + g * 4;
    float4 wn = *(const float4*)&wn_l[e0];
#pragma unroll
    for (int mt = 0; mt < 4; ++mt) {
#pragma unroll
      for (int r = 0; r < 4; ++r) {
        float sc = ((const float*)&wn)[r] - acc[mt][r];
        int e = e0 + r;
        if (sc < b1[mt]) { b3[mt] = b2[mt]; b2[mt] = b1[mt]; i2[mt] = i1[mt]; b1[mt] = sc; i1[mt] = e; }
        else if (sc < b2[mt]) { b3[mt] = b2[mt]; b2[mt] = sc; i2[mt] = e; }
        else if (sc < b3[mt]) { b3[mt] = sc; }
      }
    }
  }

  __syncthreads();   // w tiles dead; overlay merge arrays on wuni (x stays live!)
  float (*cb1)[17] = (float(*)[17])wuni;
  float (*cb2)[17] = (float(*)[17])(wuni + 4352);
  float (*cb3)[17] = (float(*)[17])(wuni + 8704);
  int   (*ci1)[17] = (int(*)[17])(wuni + 13056);
  int   (*ci2)[17] = (int(*)[17])(wuni + 17408);

#pragma unroll
  for (int mt = 0; mt < 4; ++mt) {
    int m = mt * 16 + col, slot = wv * 4 + g;
    cb1[m][slot] = b1[mt]; cb2[m][slot] = b2[mt]; cb3[m][slot] = b3[mt];
    ci1[m][slot] = i1[mt]; ci2[m][slot] = i2[mt];
  }
  __syncthreads();

  if (tid < MT) {
    const int vec = tid;
    float m1 = 1e30f, m2 = 1e30f, m3 = 1e30f;
    int j1 = 0x7fffffff, j2 = 0x7fffffff;
    auto ins = [&](float v, int ix) {
      bool q1 = (v < m1) || (v == m1 && ix < j1);
      bool q2 = (v < m2) || (v == m2 && ix < j2);
      if (q1)      { m3 = m2; m2 = m1; j2 = j1; m1 = v; j1 = ix; }
      else if (q2) { m3 = m2; m2 = v; j2 = ix; }
      else if (v < m3) { m3 = v; }
    };
    for (int t = 0; t < 16; ++t) {
      ins(cb1[vec][t], ci1[vec][t]);
      ins(cb2[vec][t], ci2[vec][t]);
      ins(cb3[vec][t], 0x7fffffff);   // 3rd-best can only land in slot 3 (value-only)
    }
    int bi = j1;
    const size_t xoff = ibase + s0 + vec;
    if (m3 - m1 < TIE_T) {
      // 3-way near-tie: full exact scan (vanishingly rare)
      double bd = 1e300; int bj = 0;
      for (int e = 0; e < EDIM; ++e) {
        double a = score64(in, wt, xoff, e);
        if (a < bd) { bd = a; bj = e; }
      }
      bi = bj;
    } else if (m2 - m1 < TIE_T) {
      double s1 = score64(in, wt, xoff, j1);
      double s2 = score64(in, wt, xoff, j2);
      if (s2 < s1 || (s2 == s1 && j2 < j1)) bi = j2;
    }
    sIdx[vec] = bi;
    atomicAdd(&hist[bi], 1);
  }
  __syncthreads();

  // ---- out_q + loss: x reconstructed from LDS hi/lo (saves the 134MB global re-read)
  {
    const int vec = tid & (MT - 1);
    const int qd  = tid >> 6;               // 4 quarters of 32 channels
    const int bi  = sIdx[vec];
    const float* wq = wt + (size_t)bi * CDIM;
    const size_t gbase = ibase + s0 + vec;
    double ls = 0.0;
#pragma unroll
    for (int cc = 0; cc < 32; cc += 4) {
      int c = qd * 32 + cc;
      int eb = (vec >> 4) * 2176 + (c >> 3) * 136 + (vec & 15) * 8 + (c & 7);
      uint2 hq = *(const uint2*)&xhi[eb];
      uint2 lq = *(const uint2*)&xlo[eb];
      float xs0 = bf2f((unsigned short)(hq.x & 0xffffu)) + bf2f((unsigned short)(lq.x & 0xffffu));
      float xs1 = bf2f((unsigned short)(hq.x >> 16))     + bf2f((unsigned short)(lq.x >> 16));
      float xs2 = bf2f((unsigned short)(hq.y & 0xffffu)) + bf2f((unsigned short)(lq.y & 0xffffu));
      float xs3 = bf2f((unsigned short)(hq.y >> 16))     + bf2f((unsigned short)(lq.y >> 16));
      float4 qv = *(const float4*)(wq + c);
      __builtin_nontemporal_store(qv.x, out_q + gbase + (size_t)(c + 0) * SPATIAL);
      __builtin_nontemporal_store(qv.y, out_q + gbase + (size_t)(c + 1) * SPATIAL);
      __builtin_nontemporal_store(qv.z, out_q + gbase + (size_t)(c + 2) * SPATIAL);
      __builtin_nontemporal_store(qv.w, out_q + gbase + (size_t)(c + 3) * SPATIAL);
      double d0 = (double)qv.x - (double)xs0; ls = fma(d0, d0, ls);
      double d1 = (double)qv.y - (double)xs1; ls = fma(d1, d1, ls);
      double d2 = (double)qv.z - (double)xs2; ls = fma(d2, d2, ls);
      double d3 = (double)qv.w - (double)xs3; ls = fma(d3, d3, ls);
    }
    lred[tid] = ls;
  }
  __syncthreads();
  for (int off = BLK / 2; off > 0; off >>= 1) {
    if (tid < off) lred[tid] += lred[tid + off];
    __syncthreads();
  }
  if (tid == 0) atomicAdd(&ws->lossAcc, lred[0]);

  // ---- encodings: 64 one-hot rows, 256 float2 columns (enc base is 8B-aligned)
  {
    const size_t r0 = (size_t)blockIdx.x * MT;
    const int c0 = tid * 2;
    unsigned long long* e2 = (unsigned long long*)enc;
    for (int r = 0; r < MT; ++r) {
      int idx = sIdx[r];
      union { float2 f; unsigned long long u; } cvt;
      cvt.f.x = (idx == c0) ? 1.0f : 0.0f;
      cvt.f.y = (idx == c0 + 1) ? 1.0f : 0.0f;
      __builtin_nontemporal_store(cvt.u, e2 + (r0 + (size_t)r) * (EDIM / 2) + tid);
    }
  }

  for (int e = tid; e < EDIM; e += BLK) {
    int v = hist[e];
    if (v) atomicAdd(&ws->counts[e], v);
  }
}

// ---- finalize
__global__ __launch_bounds__(512) void vq_fin(const WS* __restrict__ ws, float* __restrict__ out) {
  __shared__ double red[EDIM];
  int t = threadIdx.x;
  double p = (double)ws->counts[t] * (1.0 / (double)NVEC);
  red[t] = p * log(p + 1e-10);
  __syncthreads();
  for (int off = 256; off > 0; off >>= 1) {
    if (t < off) red[t] += red[t + off];
    __syncthreads();
  }
  if (t == 0) {
    out[0] = (float)(1.25 * ws->lossAcc / (double)QELEMS);
    out[1 + QELEMS] = (float)exp(-red[0]);
  }
}

extern "C" void kernel_launch(void* const* d_in, const int* in_sizes, int n_in,
                              void* d_out, int out_size, void* d_ws, size_t ws_size,
                              hipStream_t stream) {
  const float* in = (const float*)d_in[0];
  const float* wt = (const float*)d_in[1];
  float* out = (float*)d_out;
  WS* ws = (WS*)d_ws;

  float* out_q = out + 1;
  float* enc   = out + 2 + QELEMS;

  const bool useWP = (ws_size >= sizeof(WS));
  vq_pre<<<dim3(1), dim3(512), 0, stream>>>(wt, ws, useWP ? 1 : 0);
  if (useWP)
    vq_main<true><<<dim3(NVEC / MT), dim3(BLK), 0, stream>>>(in, wt, ws, out_q, enc);
  else
    vq_main<false><<<dim3(NVEC / MT), dim3(BLK), 0, stream>>>(in, wt, ws, out_q, enc);
  vq_fin<<<dim3(1), dim3(512), 0, stream>>>(ws, out);
}